// Round 4
// baseline (11393.095 us; speedup 1.0000x reference)
//
#include <hip/hip_runtime.h>
#include <hip/hip_bf16.h>
#include <stdint.h>

// Problem constants
#define B_      1024
#define T_      120
#define SENSORY 65
#define H_      512
#define RULE    64
#define NTASK   50
#define ENC_H   128
#define OUT_    33
#define IN_DIM  129     // RULE + SENSORY
#define G3      1536    // 3*H
#define INFO_DUR 20

// d_out layout (f32, concatenated): out (B*T*33) | rnn_hid (B*T*512) | rule_enc (B*64)
#define OUT_ELEMS  (B_ * T_ * OUT_)          // 4,055,040
#define HID_ELEMS  (B_ * T_ * H_)            // 62,914,560
#define HID_OFF    OUT_ELEMS
#define RENC_OFF   (OUT_ELEMS + HID_ELEMS)   // 66,969,600

__device__ __forceinline__ float sigmoidf_(float x) {
    return 1.f / (1.f + __expf(-x));
}

// ---------------------------------------------------------------------------
// K_init: fill h0 with 0.1f
__global__ void init_h_kernel(float* __restrict__ h) {
    int i = blockIdx.x * 256 + threadIdx.x;   // grid sized exactly
    h[i] = 0.1f;
}

// ---------------------------------------------------------------------------
// K0: encoder — rule_t = task_rule @ rule_transform; h1 = relu(rule_t@enc_w1^T+b1);
//     rule_enc = relu(h1@enc_w2^T+b2). One block (128 thr) per batch row.
__global__ void __launch_bounds__(128) enc_kernel(
    const float* __restrict__ task_rule, const float* __restrict__ rule_transform,
    const float* __restrict__ enc_w1, const float* __restrict__ enc_b1,
    const float* __restrict__ enc_w2, const float* __restrict__ enc_b2,
    float* __restrict__ renc_out)
{
    int b = blockIdx.x;
    int tid = threadIdx.x;
    __shared__ float tr_s[NTASK];
    __shared__ float rt_s[RULE];
    __shared__ float h1_s[ENC_H];

    if (tid < NTASK) tr_s[tid] = task_rule[b * NTASK + tid];
    __syncthreads();
    if (tid < RULE) {
        float acc = 0.f;
        for (int n = 0; n < NTASK; ++n)
            acc += tr_s[n] * rule_transform[n * RULE + tid];
        rt_s[tid] = acc;
    }
    __syncthreads();
    {   // h1, 128 threads
        float acc = 0.f;
        for (int k = 0; k < RULE; ++k)
            acc += rt_s[k] * enc_w1[tid * RULE + k];
        acc += enc_b1[tid];
        h1_s[tid] = fmaxf(acc, 0.f);
    }
    __syncthreads();
    if (tid < RULE) {
        float acc = 0.f;
        for (int i = 0; i < ENC_H; ++i)
            acc += h1_s[i] * enc_w2[tid * ENC_H + i];
        acc += enc_b2[tid];
        renc_out[b * RULE + tid] = fmaxf(acc, 0.f);
    }
}

// ---------------------------------------------------------------------------
// K1: rule_gi[b][g] = sum_k renc[b][k] * w_ih[g][k]   (k < 64)
__global__ void __launch_bounds__(256) rulegi_kernel(
    const float* __restrict__ renc, const float* __restrict__ w_ih,
    float* __restrict__ rule_gi)
{
    int id = blockIdx.x * 256 + threadIdx.x;   // grid exact: B*G3/256
    int b = id / G3, g = id % G3;
    const float* r = renc + b * RULE;
    const float* w = w_ih + (size_t)g * IN_DIM;
    float acc = 0.f;
#pragma unroll 8
    for (int k = 0; k < RULE; ++k) acc += r[k] * w[k];
    rule_gi[id] = acc;
}

// ---------------------------------------------------------------------------
// K2: one GRU step.  Tile: BM=32 batch x BJ=32 hidden, 128 threads,
// each thread: TM=4 batch x TN=2 hidden x {r,z,h_n,i_n} accumulators.
// h state chains through the f32 hid output region: h_src row stride is
// hs_stride (H for the t=0 init buffer, T*H inside hid); dst is hid + t*H
// with batch stride T*H.
#define BM 32
#define BJ 32
#define BK 32
#define APAD 36
__global__ void __launch_bounds__(128) step_kernel(
    const float* __restrict__ h_src, int hs_stride, float* __restrict__ h_dst,
    const float* __restrict__ x, const float* __restrict__ w_ih,
    const float* __restrict__ w_hh, const float* __restrict__ b_ih,
    const float* __restrict__ b_hh, const float* __restrict__ rule_gi,
    int t)
{
    __shared__ float a_s[BK][APAD];          // [k][b]
    __shared__ float w_s[3][BK][APAD];       // [gate][k][j]

    const int tid = threadIdx.x;
    const int tx = tid & 15;          // j: tx*2 .. +1
    const int ty = tid >> 4;          // b: ty*4 .. +3
    const int b0 = blockIdx.x * BM;
    const int j0 = blockIdx.y * BJ;

    float acc[4][4][2];               // [r,z,hn,in][TM][TN]
#pragma unroll
    for (int g = 0; g < 4; ++g)
#pragma unroll
        for (int i = 0; i < 4; ++i) { acc[g][i][0] = 0.f; acc[g][i][1] = 0.f; }

    // ---- 16 chunks over the hidden state (K = 512) ----
    for (int c = 0; c < 16; ++c) {
        const int k0 = c * BK;
        __syncthreads();
        // load h tile (f32) -> a_s[k][b]
#pragma unroll
        for (int m = 0; m < 2; ++m) {
            int v = tid + m * 128;            // 0..255 float4 vectors
            int bl = v >> 3;
            int kl = (v & 7) << 2;
            float4 hv = *(const float4*)&h_src[(size_t)(b0 + bl) * hs_stride + k0 + kl];
            a_s[kl + 0][bl] = hv.x; a_s[kl + 1][bl] = hv.y;
            a_s[kl + 2][bl] = hv.z; a_s[kl + 3][bl] = hv.w;
        }
        // load w_hh tile (f32) -> w_s[g][k][j]
#pragma unroll
        for (int m = 0; m < 6; ++m) {
            int v = tid + m * 128;            // 0..767 float4 vectors
            int g  = v >> 8;
            int rem = v & 255;
            int jl = rem >> 3;
            int kl = (rem & 7) << 2;
            float4 wv = *(const float4*)&w_hh[(size_t)(g * H_ + j0 + jl) * H_ + k0 + kl];
            w_s[g][kl + 0][jl] = wv.x; w_s[g][kl + 1][jl] = wv.y;
            w_s[g][kl + 2][jl] = wv.z; w_s[g][kl + 3][jl] = wv.w;
        }
        __syncthreads();
#pragma unroll
        for (int kk = 0; kk < BK; ++kk) {
            float4 hv = *(const float4*)&a_s[kk][ty * 4];
#pragma unroll
            for (int g = 0; g < 3; ++g) {
                float w0 = w_s[g][kk][tx * 2 + 0];
                float w1 = w_s[g][kk][tx * 2 + 1];
                acc[g][0][0] += hv.x * w0; acc[g][0][1] += hv.x * w1;
                acc[g][1][0] += hv.y * w0; acc[g][1][1] += hv.y * w1;
                acc[g][2][0] += hv.z * w0; acc[g][2][1] += hv.z * w1;
                acc[g][3][0] += hv.w * w0; acc[g][3][1] += hv.w * w1;
            }
        }
    }

    // ---- 3 chunks over the sensory input (K = 65, padded to 96) ----
    for (int cx = 0; cx < 3; ++cx) {
        const int s0 = cx * BK;
        __syncthreads();
#pragma unroll
        for (int m = 0; m < 8; ++m) {
            int e = tid + m * 128;            // 0..1023 scalars
            int sl = e & 31, bl = e >> 5;
            int s = s0 + sl;
            float val = 0.f;
            if (s < SENSORY)
                val = x[((size_t)(b0 + bl) * T_ + t) * SENSORY + s];
            a_s[sl][bl] = val;
        }
#pragma unroll
        for (int m = 0; m < 24; ++m) {
            int e = tid + m * 128;            // 0..3071 scalars
            int g = e >> 10;
            int rem = e & 1023;
            int jl = rem >> 5, sl = rem & 31;
            int s = s0 + sl;
            float val = 0.f;
            if (s < SENSORY)
                val = w_ih[(size_t)(g * H_ + j0 + jl) * IN_DIM + RULE + s];
            w_s[g][sl][jl] = val;
        }
        __syncthreads();
#pragma unroll
        for (int kk = 0; kk < BK; ++kk) {
            float4 hv = *(const float4*)&a_s[kk][ty * 4];
#pragma unroll
            for (int g = 0; g < 3; ++g) {
                int ga = (g == 2) ? 3 : g;    // x-part of gate n -> i_n accumulator
                float w0 = w_s[g][kk][tx * 2 + 0];
                float w1 = w_s[g][kk][tx * 2 + 1];
                acc[ga][0][0] += hv.x * w0; acc[ga][0][1] += hv.x * w1;
                acc[ga][1][0] += hv.y * w0; acc[ga][1][1] += hv.y * w1;
                acc[ga][2][0] += hv.z * w0; acc[ga][2][1] += hv.z * w1;
                acc[ga][3][0] += hv.w * w0; acc[ga][3][1] += hv.w * w1;
            }
        }
    }

    // ---- epilogue: gates + state update ----
    const bool use_rule = (t < INFO_DUR);
#pragma unroll
    for (int jj = 0; jj < 2; ++jj) {
        int j = j0 + tx * 2 + jj;
        float bihr = b_ih[j];
        float bihz = b_ih[H_ + j];
        float bihn = b_ih[2 * H_ + j];
        float bhhr = b_hh[j];
        float bhhz = b_hh[H_ + j];
        float bhhn = b_hh[2 * H_ + j];
#pragma unroll
        for (int i = 0; i < 4; ++i) {
            int b = b0 + ty * 4 + i;
            float rg_r = 0.f, rg_z = 0.f, rg_n = 0.f;
            if (use_rule) {
                const float* rg = rule_gi + (size_t)b * G3;
                rg_r = rg[j]; rg_z = rg[H_ + j]; rg_n = rg[2 * H_ + j];
            }
            float r  = sigmoidf_(acc[0][i][jj] + bihr + bhhr + rg_r);
            float z  = sigmoidf_(acc[1][i][jj] + bihz + bhhz + rg_z);
            float hn = acc[2][i][jj] + bhhn;
            float in = acc[3][i][jj] + bihn + rg_n;
            float n  = fmaxf(in + r * hn, 0.f);
            float ho = h_src[(size_t)b * hs_stride + j];
            float hnew = (1.f - z) * n + z * ho;
            h_dst[(size_t)b * (T_ * H_) + j] = hnew;   // = rnn_hid[b][t][j]
        }
    }
}

// ---------------------------------------------------------------------------
// K3: out[bt][o] = sigmoid(rnn_hid[bt] . out_w[o] + out_b[o]) — 16 rows/block.
#define BT_TILE 16
#define RPAD 516
__global__ void __launch_bounds__(256) out_kernel(
    const float* __restrict__ hid, const float* __restrict__ out_w,
    const float* __restrict__ out_b, float* __restrict__ out)
{
    __shared__ float rnn_s[BT_TILE][RPAD];
    const int tid = threadIdx.x;
    const int bt0 = blockIdx.x * BT_TILE;

    for (int v = tid; v < (BT_TILE * H_) / 4; v += 256) {
        int r = v >> 7;
        int kl = (v & 127) << 2;
        float4 hv = *(const float4*)&hid[(size_t)(bt0 + r) * H_ + kl];
        *(float4*)&rnn_s[r][kl] = hv;
    }
    __syncthreads();

    for (int idx = tid; idx < BT_TILE * OUT_; idx += 256) {
        int r = idx / OUT_;
        int o = idx % OUT_;
        const float* rp = rnn_s[r];
        const float* wp = out_w + (size_t)o * H_;
        float acc = 0.f;
#pragma unroll 4
        for (int k = 0; k < H_; k += 4) {
            float4 av = *(const float4*)(rp + k);
            float4 wv = *(const float4*)(wp + k);
            acc = fmaf(av.x, wv.x, acc);
            acc = fmaf(av.y, wv.y, acc);
            acc = fmaf(av.z, wv.z, acc);
            acc = fmaf(av.w, wv.w, acc);
        }
        acc += out_b[o];
        out[(size_t)(bt0 + r) * OUT_ + o] = sigmoidf_(acc);
    }
}

// ---------------------------------------------------------------------------
extern "C" void kernel_launch(void* const* d_in, const int* in_sizes, int n_in,
                              void* d_out, int out_size, void* d_ws, size_t ws_size,
                              hipStream_t stream)
{
    const float* x              = (const float*)d_in[0];
    const float* task_rule      = (const float*)d_in[1];
    const float* rule_transform = (const float*)d_in[2];
    const float* enc_w1         = (const float*)d_in[3];
    const float* enc_b1         = (const float*)d_in[4];
    const float* enc_w2         = (const float*)d_in[5];
    const float* enc_b2         = (const float*)d_in[6];
    const float* w_ih           = (const float*)d_in[7];
    const float* w_hh           = (const float*)d_in[8];
    const float* b_ih           = (const float*)d_in[9];
    const float* b_hh           = (const float*)d_in[10];
    const float* out_w          = (const float*)d_in[11];
    const float* out_b          = (const float*)d_in[12];

    float* out_p  = (float*)d_out;                 // B*T*33
    float* hid_p  = (float*)d_out + HID_OFF;       // B*T*512
    float* renc_p = (float*)d_out + RENC_OFF;      // B*64

    float* ws      = (float*)d_ws;
    float* rule_gi = ws;                            // B*G3 = 1,572,864 f32
    float* hinit   = rule_gi + (size_t)B_ * G3;     // B*H  =   524,288 f32

    // h0 = 0.1
    init_h_kernel<<<(B_ * H_) / 256, 256, 0, stream>>>(hinit);
    // encoder -> rule_enc (f32, directly into d_out region)
    enc_kernel<<<B_, 128, 0, stream>>>(task_rule, rule_transform, enc_w1, enc_b1,
                                       enc_w2, enc_b2, renc_p);
    // rule projection into gate space
    rulegi_kernel<<<(B_ * G3) / 256, 256, 0, stream>>>(renc_p, w_ih, rule_gi);

    // GRU scan — state chains through the f32 hid output region
    for (int t = 0; t < T_; ++t) {
        const float* hs = (t == 0) ? hinit : (hid_p + (size_t)(t - 1) * H_);
        int stride      = (t == 0) ? H_ : (T_ * H_);
        float* hd       = hid_p + (size_t)t * H_;
        step_kernel<<<dim3(B_ / BM, H_ / BJ), 128, 0, stream>>>(
            hs, stride, hd, x, w_ih, w_hh, b_ih, b_hh, rule_gi, t);
    }

    // output projection
    out_kernel<<<(B_ * T_) / BT_TILE, 256, 0, stream>>>(hid_p, out_w, out_b, out_p);
}